// Round 2
// baseline (775.283 us; speedup 1.0000x reference)
//
#include <hip/hip_runtime.h>
#include <hip/hip_bf16.h>

// y_n = tanh(W_n @ sum_k values[idx[n,k]] + b_n)
//   M=1e6, D=16, N=500000, K=8.
//
// Two-phase split:
//   Phase 1 (gather_sum): s[n] = sum_k values[idx[n,k]]  -- working set is
//     values (64 MB) + idx (16 MB) + s (32 MB) = 112 MB < 256 MB L3, so the
//     random gathers hit L3 instead of missing to HBM.
//   Phase 2 (matvec): y = tanh(W_n @ s_n + b_n) -- pure streaming of W
//     (512 MB) + b + s + out at HBM line efficiency.
// The R0 fused kernel thrashed L3 with the W stream, pushing 256 MB of
// random gathers out to HBM (~0.9 TB/s effective).

#define D_DIM 16
#define K_FAN 8
#define NPB 16   // neurons per block: 16 x 16 lanes = 256 threads

__global__ __launch_bounds__(256)
void gather_sum_kernel(const float* __restrict__ values,   // [M,16]
                       const int*   __restrict__ idx,      // [N,8]
                       float*       __restrict__ s_out,    // [N,16]
                       int N)
{
    __shared__ int idx_sm[NPB][K_FAN];

    const int t  = threadIdx.x;
    const int nl = t >> 4;
    const int i  = t & 15;
    const int n0 = blockIdx.x * NPB;
    const int n  = n0 + nl;

    if (t < NPB * K_FAN) {
        const int g = n0 * K_FAN + t;
        idx_sm[t >> 3][t & 7] = (g < N * K_FAN) ? idx[g] : 0;
    }
    __syncthreads();

    if (n < N) {
        float s = 0.0f;
        #pragma unroll
        for (int k = 0; k < K_FAN; ++k) {
            const long long row = (long long)idx_sm[nl][k];
            s += values[row * D_DIM + i];   // 64B coalesced segment per row
        }
        s_out[(long long)n * D_DIM + i] = s;
    }
}

__global__ __launch_bounds__(256)
void matvec_kernel(const float* __restrict__ s_in,   // [N,16]
                   const float* __restrict__ W,      // [N,16,16]
                   const float* __restrict__ b,      // [N,16]
                   float*       __restrict__ out,    // [N,16]
                   int N)
{
    __shared__ float s_sm[NPB][D_DIM];

    const int t  = threadIdx.x;
    const int nl = t >> 4;
    const int i  = t & 15;
    const int n0 = blockIdx.x * NPB;
    const int n  = n0 + nl;

    // Coalesced load of this block's 256 s-values.
    {
        const long long g = (long long)n0 * D_DIM + t;
        s_sm[t >> 4][t & 15] = (g < (long long)N * D_DIM) ? s_in[g] : 0.0f;
    }
    __syncthreads();

    if (n < N) {
        // Each thread: contiguous 64B W-row as 4x float4; the 4 unrolled
        // loads fully cover every 64B line across the wave.
        const float4* Wv = (const float4*)(W + (long long)n * (D_DIM * D_DIM) + i * D_DIM);
        float acc = b[(long long)n * D_DIM + i];
        #pragma unroll
        for (int j4 = 0; j4 < 4; ++j4) {
            const float4 w = Wv[j4];
            acc += w.x * s_sm[nl][4 * j4 + 0];
            acc += w.y * s_sm[nl][4 * j4 + 1];
            acc += w.z * s_sm[nl][4 * j4 + 2];
            acc += w.w * s_sm[nl][4 * j4 + 3];
        }
        out[(long long)n * D_DIM + i] = tanhf(acc);
    }
}

extern "C" void kernel_launch(void* const* d_in, const int* in_sizes, int n_in,
                              void* d_out, int out_size, void* d_ws, size_t ws_size,
                              hipStream_t stream) {
    const float* values = (const float*)d_in[0];   // [M,16] fp32
    const int*   idx    = (const int*)  d_in[1];   // [N,8]  int32
    const float* W      = (const float*)d_in[2];   // [N,16,16] fp32
    const float* b      = (const float*)d_in[3];   // [N,16] fp32
    float*       out    = (float*)d_out;
    float*       s_buf  = (float*)d_ws;            // [N,16] scratch (32 MB)

    const int N = in_sizes[3] / D_DIM;             // 500000
    const int blocks = (N + NPB - 1) / NPB;        // 31250

    gather_sum_kernel<<<blocks, 256, 0, stream>>>(values, idx, s_buf, N);
    matvec_kernel<<<blocks, 256, 0, stream>>>(s_buf, W, b, out, N);
}